// Round 7
// baseline (330.231 us; speedup 1.0000x reference)
//
#include <hip/hip_runtime.h>
#include <math.h>
#include <stdint.h>

#define ROWS 4096
#define COLS 8192
#define KSEL 4096
#define NT 256
#define NWAVE (NT / 64)
#define PT (COLS / (4 * NT))   // float4s per thread per row = 8
#define NBINS 1024             // bins over u in [0, 0.75)
#define WMAX 128
#define RANGE_HI 0.75f
#define LN2F 0.69314718056f

typedef float fvec4 __attribute__((ext_vector_type(4)));

// Algorithm (rounds 1-5): u = z + gumbel, bulk classify via 1024-bin hist of
// fast-u; exact fp64-chain re-resolve only for bins B-1..B+1 (~6/row).
// R5: clamp bins 0/1023 counted in regs (bank conflicts 1.4e7->7e5, verified).
//
// R11 (de-risked R10): two rows/block, software-pipelined.
//  - Theory: all blocks run load/think phases in lockstep => memory idle ~60%
//    (274MB HBM in 117us = 37% active). Overlap row1's 16 asm loads with
//    row0's scan + hist re-zero (LDS/VALU only), and row0's stores with
//    row1's scan, via lgkm-only raw barriers (no __syncthreads vmcnt drain).
//  - R10 crash root-cause guess: launch_bounds(,4) VGPR cap 128 < ~130 live
//    => allocator spilled ASYNC asm-load outputs => fault. Fix: bounds(NT,2)
//    cap 256, ~120 live, no spill. Verify: VGPR_Count 110-140, scratch 0.
//  - Clean ledger: row1 consumed BEFORE row0's pass2 stores, so between
//    issue(D) and consume(G) there are zero compiler vmem ops (scan+re-zero
//    are LDS/VALU, bracketed by "memory"-clobber asm walls) => waits are the
//    R5-proven vmcnt(14..0).
__device__ __forceinline__ int bin_of(float u) {
    int b = (int)(u * ((float)NBINS / RANGE_HI));
    b = b < 0 ? 0 : b;
    b = b > NBINS - 1 ? NBINS - 1 : b;
    return b;
}

#define LGKM_BAR() do { \
    asm volatile("s_waitcnt lgkmcnt(0)" ::: "memory"); \
    __builtin_amdgcn_s_barrier(); } while (0)

#define FULL_BAR() do { \
    asm volatile("s_waitcnt vmcnt(0) lgkmcnt(0)" ::: "memory"); \
    __builtin_amdgcn_s_barrier(); } while (0)

__global__ __launch_bounds__(NT, 2) void mask_topk_kernel(
    const float* __restrict__ z, const float* __restrict__ eps,
    float* __restrict__ out)
{
    __shared__ uint32_t hist[NWAVE][NBINS];   // 16 KB
    __shared__ uint32_t wtot[NWAVE];
    __shared__ int      winIdx[WMAX];
    __shared__ uint32_t winSig[WMAX];
    __shared__ int      s_B, s_need2;
    __shared__ uint32_t s_SB, s_wcount;

    const int tid  = threadIdx.x;
    const int lane = tid & 63;
    const int wave = tid >> 6;
    const size_t rb0 = (size_t)(blockIdx.x * 2) * COLS;
    const size_t rb1 = rb0 + COLS;

#define ISSUE_LOADS(ZR, ER, RB) do {                                          \
    const fvec4* z4_ = (const fvec4*)(z + (RB));                              \
    const fvec4* e4_ = (const fvec4*)(eps + (RB));                            \
    _Pragma("unroll")                                                         \
    for (int it = 0; it < PT; ++it) {                                         \
        const fvec4* zp_ = z4_ + (it * NT + tid);                             \
        const fvec4* ep_ = e4_ + (it * NT + tid);                             \
        asm volatile("global_load_dwordx4 %0, %1, off" : "=v"(ZR[it]) : "v"(zp_)); \
        asm volatile("global_load_dwordx4 %0, %1, off" : "=v"(ER[it]) : "v"(ep_)); \
    }                                                                         \
    __builtin_amdgcn_sched_barrier(0);                                        \
} while (0)

// consume one float4-pair: staged vmcnt wait, compute u, hist, packed bins
#define CSTEP(ZR, ER, PB, IT, VMN, CLO, CHI) do {                             \
    asm volatile("s_waitcnt vmcnt(" #VMN ")");                                \
    __builtin_amdgcn_sched_barrier(0);                                        \
    float zz_[4] = {ZR[IT].x, ZR[IT].y, ZR[IT].z, ZR[IT].w};                  \
    float ee_[4] = {ER[IT].x, ER[IT].y, ER[IT].z, ER[IT].w};                  \
    uint32_t bb_[4];                                                          \
    _Pragma("unroll")                                                         \
    for (int j = 0; j < 4; ++j) {                                             \
        float l1_ = __builtin_amdgcn_logf(ee_[j]) * LN2F;                     \
        float l2_ = __builtin_amdgcn_logf(-l1_) * LN2F;                       \
        float u_  = zz_[j] - l2_;                                             \
        int b_ = bin_of(u_);                                                  \
        if (b_ == 0)              ++CLO;                                      \
        else if (b_ == NBINS - 1) ++CHI;                                      \
        else atomicAdd(&hist[wave][b_], 1u);                                  \
        bb_[j] = (uint32_t)b_;                                                \
    }                                                                         \
    PB[2*(IT)]   = bb_[0] | (bb_[1] << 16);                                   \
    PB[2*(IT)+1] = bb_[2] | (bb_[3] << 16);                                   \
} while (0)

#define CLAMP_REDUCE(CLO, CHI) do {                                           \
    _Pragma("unroll")                                                         \
    for (int off = 32; off >= 1; off >>= 1) {                                 \
        CLO += __shfl_down(CLO, off, 64);                                     \
        CHI += __shfl_down(CHI, off, 64);                                     \
    }                                                                         \
    if (lane == 0) {                                                          \
        atomicAdd(&hist[wave][0],         CLO);                               \
        atomicAdd(&hist[wave][NBINS - 1], CHI);                               \
    }                                                                         \
} while (0)

#define SCAN_PICK(BOUT, NOUT) do {                                            \
    const int hb_ = tid * (NBINS / NT);                                       \
    uint32_t h_[NBINS / NT]; uint32_t cs_ = 0;                                \
    _Pragma("unroll")                                                         \
    for (int i = 0; i < NBINS / NT; ++i) {                                    \
        uint32_t t_ = 0;                                                      \
        _Pragma("unroll")                                                     \
        for (int c = 0; c < NWAVE; ++c) t_ += hist[c][hb_ + i];               \
        h_[i] = t_; cs_ += t_;                                                \
    }                                                                         \
    uint32_t v_ = cs_;                                                        \
    _Pragma("unroll")                                                         \
    for (int off = 1; off < 64; off <<= 1) {                                  \
        uint32_t t_ = __shfl_down(v_, off, 64);                               \
        if (lane + off < 64) v_ += t_;                                        \
    }                                                                         \
    if (lane == 0) wtot[wave] = v_;                                           \
    LGKM_BAR();                                                               \
    uint32_t above_ = 0;                                                      \
    _Pragma("unroll")                                                         \
    for (int c = 0; c < NWAVE; ++c) above_ += (c > wave) ? wtot[c] : 0u;      \
    uint32_t cum_ = (v_ + above_) - cs_;                                      \
    for (int i = NBINS / NT - 1; i >= 0; --i) {                               \
        if (cum_ < KSEL && KSEL <= cum_ + h_[i]) { s_B = hb_ + i; s_SB = cum_; } \
        cum_ += h_[i];                                                        \
    }                                                                         \
    LGKM_BAR();                                                               \
    if (tid == 0) {                                                           \
        uint32_t hB1_ = 0; int Bq_ = s_B;                                     \
        if (Bq_ + 1 < NBINS)                                                  \
            for (int c = 0; c < NWAVE; ++c) hB1_ += hist[c][Bq_ + 1];         \
        s_need2 = KSEL - (int)(s_SB - hB1_);                                  \
    }                                                                         \
    LGKM_BAR();                                                               \
    BOUT = s_B; NOUT = s_need2;                                               \
} while (0)

#define PASS2_STORE(PB, RB, BQ) do {                                          \
    fvec4* o4_ = (fvec4*)(out + (RB));                                        \
    _Pragma("unroll")                                                         \
    for (int it = 0; it < PT; ++it) {                                         \
        const int k_ = it * NT + tid;                                         \
        int b_[4] = { (int)(PB[2*it] & 0xffffu), (int)(PB[2*it] >> 16),       \
                      (int)(PB[2*it+1] & 0xffffu), (int)(PB[2*it+1] >> 16) }; \
        float oo_[4];                                                         \
        _Pragma("unroll")                                                     \
        for (int j = 0; j < 4; ++j) {                                         \
            oo_[j] = (b_[j] > (BQ) + 1) ? 1.0f : 0.0f;                        \
            if (b_[j] >= (BQ) - 1 && b_[j] <= (BQ) + 1) {                     \
                uint32_t slot_ = atomicAdd(&s_wcount, 1u);                    \
                if (slot_ < WMAX) winIdx[slot_] = k_ * 4 + j;                 \
            }                                                                 \
        }                                                                     \
        fvec4 ov_; ov_.x = oo_[0]; ov_.y = oo_[1]; ov_.z = oo_[2]; ov_.w = oo_[3]; \
        o4_[k_] = ov_;                                                        \
    }                                                                         \
} while (0)

#define TAILSIG(RB, W) do {                                                   \
    if (tid < 64) {                                                           \
        for (int j = lane; j < (W); j += 64) {                                \
            int idx_ = winIdx[j];                                             \
            float e_  = eps[(RB) + idx_];                                     \
            float zz_ = z[(RB) + idx_];                                       \
            float l1_ = (float)log((double)e_);                               \
            float l2_ = (float)log((double)(-l1_));                           \
            float g_  = -l2_;                                                 \
            float s_  = zz_ + g_;                                             \
            float t_  = s_ / (2.0f / 3.0f);                                   \
            float ex_ = (float)exp(-(double)t_);                              \
            float sig_ = 1.0f / (1.0f + ex_);                                 \
            winSig[j] = __float_as_uint(sig_);                                \
        }                                                                     \
    }                                                                         \
} while (0)

#define TAILRANK(RB, W, NEED) do {                                            \
    if (tid < 64) {                                                           \
        for (int j = lane; j < (W); j += 64) {                                \
            uint32_t sj_ = winSig[j]; int ij_ = winIdx[j]; int rank_ = 0;     \
            for (int kk = 0; kk < (W); ++kk) {                                \
                uint32_t sk_ = winSig[kk]; int ik_ = winIdx[kk];              \
                rank_ += (sk_ > sj_ || (sk_ == sj_ && ik_ < ij_)) ? 1 : 0;    \
            }                                                                 \
            out[(RB) + ij_] = (rank_ < (NEED)) ? 1.0f : 0.0f;                 \
        }                                                                     \
    }                                                                         \
} while (0)

    // ---- A: issue row0's 16 loads (asm: cannot be sunk or elided) ----
    fvec4 zr0[PT], er0[PT];
    ISSUE_LOADS(zr0, er0, rb0);

    // ---- B: hist init overlaps in-flight loads; lgkm-only barrier ----
    for (int i = tid; i < NWAVE * NBINS; i += NT) ((uint32_t*)hist)[i] = 0;
    if (tid == 0) s_wcount = 0;
    LGKM_BAR();

    // ---- C: consume row0 (16 outstanding -> staged 14..0) ----
    uint32_t pb0[2 * PT];
    uint32_t cLo0 = 0, cHi0 = 0;
    CSTEP(zr0, er0, pb0, 0, 14, cLo0, cHi0); CSTEP(zr0, er0, pb0, 1, 12, cLo0, cHi0);
    CSTEP(zr0, er0, pb0, 2, 10, cLo0, cHi0); CSTEP(zr0, er0, pb0, 3,  8, cLo0, cHi0);
    CSTEP(zr0, er0, pb0, 4,  6, cLo0, cHi0); CSTEP(zr0, er0, pb0, 5,  4, cLo0, cHi0);
    CSTEP(zr0, er0, pb0, 6,  2, cLo0, cHi0); CSTEP(zr0, er0, pb0, 7,  0, cLo0, cHi0);
    CLAMP_REDUCE(cLo0, cHi0);
    LGKM_BAR();

    // ---- D: issue row1's 16 loads; they fly across E+F (LDS/VALU only) ----
    fvec4 zr1[PT], er1[PT];
    ISSUE_LOADS(zr1, er1, rb1);

    // ---- E: row0 scan (lgkm-only barriers; row1 loads stay in flight) ----
    int B0, need0;
    SCAN_PICK(B0, need0);

    // ---- F: re-zero hist for row1 (LDS only) ----
    for (int i = tid; i < NWAVE * NBINS; i += NT) ((uint32_t*)hist)[i] = 0;
    LGKM_BAR();

    // ---- G: consume row1. Ledger clean: exactly 16 outstanding vmem ----
    uint32_t pb1[2 * PT];
    uint32_t cLo1 = 0, cHi1 = 0;
    CSTEP(zr1, er1, pb1, 0, 14, cLo1, cHi1); CSTEP(zr1, er1, pb1, 1, 12, cLo1, cHi1);
    CSTEP(zr1, er1, pb1, 2, 10, cLo1, cHi1); CSTEP(zr1, er1, pb1, 3,  8, cLo1, cHi1);
    CSTEP(zr1, er1, pb1, 4,  6, cLo1, cHi1); CSTEP(zr1, er1, pb1, 5,  4, cLo1, cHi1);
    CSTEP(zr1, er1, pb1, 6,  2, cLo1, cHi1); CSTEP(zr1, er1, pb1, 7,  0, cLo1, cHi1);
    CLAMP_REDUCE(cLo1, cHi1);
    LGKM_BAR();

    // ---- H: row0 classify + stores + window collect (stores fly onward) ----
    PASS2_STORE(pb0, rb0, B0);

    // ---- I: row1 scan overlaps row0's in-flight stores ----
    int B1, need1;
    SCAN_PICK(B1, need1);

    // ---- J: drain stores before tail's scalar overwrites of same lines ----
    FULL_BAR();

    // ---- K: row0 tail (exact fp64 chain + rank) ----
    {
        int w0 = (int)s_wcount; if (w0 > WMAX) w0 = WMAX;
        TAILSIG(rb0, w0);
        LGKM_BAR();
        TAILRANK(rb0, w0, need0);
        if (tid == 0) s_wcount = 0;
        LGKM_BAR();
    }

    // ---- L: row1 classify + stores + window collect ----
    PASS2_STORE(pb1, rb1, B1);

    // ---- M: drain row1 stores before row1 tail overwrites ----
    FULL_BAR();

    // ---- N: row1 tail ----
    {
        int w1 = (int)s_wcount; if (w1 > WMAX) w1 = WMAX;
        TAILSIG(rb1, w1);
        LGKM_BAR();
        TAILRANK(rb1, w1, need1);
    }

#undef ISSUE_LOADS
#undef CSTEP
#undef CLAMP_REDUCE
#undef SCAN_PICK
#undef PASS2_STORE
#undef TAILSIG
#undef TAILRANK
}

extern "C" void kernel_launch(void* const* d_in, const int* in_sizes, int n_in,
                              void* d_out, int out_size, void* d_ws, size_t ws_size,
                              hipStream_t stream) {
    const float* z   = (const float*)d_in[0];
    const float* eps = (const float*)d_in[1];
    float* out = (float*)d_out;
    hipLaunchKernelGGL(mask_topk_kernel, dim3(ROWS / 2), dim3(NT), 0, stream,
                       z, eps, out);
}

// Round 8
// 322.850 us; speedup vs baseline: 1.0229x; 1.0229x over previous
//
#include <hip/hip_runtime.h>
#include <math.h>
#include <stdint.h>

#define ROWS 4096
#define COLS 8192
#define KSEL 4096
#define NT 256
#define NWAVE (NT / 64)
#define PT (COLS / (4 * NT))   // float4s per thread = 8 (32 elements)
#define NBINS 1024             // bins over u in [0, 0.75); width 7.32e-4
#define WMAX 128               // window elems/row: mean ~6, P(>128) ~ 0
#define RANGE_HI 0.75f
#define LN2F 0.69314718056f

// u = z + gumbel is the (monotone) selection key; bulk classification by
// 1024-bin histogram of fast-u (hw v_log_f32 chain, err ~2e-6 near the cut),
// exact per-op-fp32-rounded fp64 chain only for the ~6 elements/row in bins
// B-1..B+1 (bitwise-proven vs numpy in the original session).
//
// R5: clamp bins 0/1023 (~75% of elems) counted in registers + one
// wave-reduced atomic each (bank-conflict 1.4e7 -> 7e5 cycles, verified).
//
// R6-R11 (forced-schedule arc, all neutral-or-worse): 16 asm-pinned
// in-flight loads/wave (R9), 2-row software pipeline at 26% occupancy
// (R11) -- BW pinned at ~2.2 TB/s throughout, insensitive to occupancy,
// MLP depth, and pipelining. Compiler-scheduled codegen (VGPR 36) is the
// champion; all asm pins removed.
//
// R12 (this round): attack the serial per-block phase overhead instead.
//  - Exact-sig folded INTO pass 2: window owners re-read e,z (L1/L2-hot,
//    overlapped with the store stream) and compute the exact fp64-rounded
//    chain inline -> TAILSIG phase + its post-drain serial latency deleted.
//  - need2 computed by the scan's unique writer (reads hist[c][B+1]
//    directly) -> one barrier + the tid==0 phase deleted.
//  - Barriers per block: 6 -> 4.
__device__ __forceinline__ int bin_of(float u) {
    int b = (int)(u * ((float)NBINS / RANGE_HI));
    b = b < 0 ? 0 : b;
    b = b > NBINS - 1 ? NBINS - 1 : b;
    return b;
}

__global__ __launch_bounds__(NT) void mask_topk_kernel(
    const float* __restrict__ z, const float* __restrict__ eps,
    float* __restrict__ out)
{
    __shared__ uint32_t hist[NWAVE][NBINS];   // 16 KB, one copy per wave
    __shared__ uint32_t wtot[NWAVE];
    __shared__ int      winIdx[WMAX];
    __shared__ uint32_t winSig[WMAX];
    __shared__ int      s_B, s_need2;
    __shared__ uint32_t s_wcount;

    const int row  = blockIdx.x;
    const int tid  = threadIdx.x;
    const int lane = tid & 63;
    const int wave = tid >> 6;
    const size_t rbase = (size_t)row * COLS;

    // ---- pass 1a: loads (compiler-scheduled; proven-best codegen) ----
    const float4* z4 = (const float4*)(z + rbase);
    const float4* e4 = (const float4*)(eps + rbase);
    float4 zr[PT], er[PT];
#pragma unroll
    for (int it = 0; it < PT; ++it) {
        zr[it] = z4[it * NT + tid];
        er[it] = e4[it * NT + tid];
    }

    // hist zero-init overlaps the in-flight loads
    for (int i = tid; i < NWAVE * NBINS; i += NT) ((uint32_t*)hist)[i] = 0;
    if (tid == 0) s_wcount = 0;
    __syncthreads();

    // ---- pass 1b: compute u in place (zr becomes u) + per-wave histogram ----
    uint32_t cLo = 0, cHi = 0;     // register counts for the two clamp bins
#pragma unroll
    for (int it = 0; it < PT; ++it) {
        float zz[4] = {zr[it].x, zr[it].y, zr[it].z, zr[it].w};
        float ee[4] = {er[it].x, er[it].y, er[it].z, er[it].w};
        float uu[4];
#pragma unroll
        for (int j = 0; j < 4; ++j) {
            float l1 = __builtin_amdgcn_logf(ee[j]) * LN2F;   // ~log(eps) < 0
            float l2 = __builtin_amdgcn_logf(-l1) * LN2F;     // ~log(-log eps)
            uu[j] = zz[j] - l2;                               // u = z + gumbel
            int b = bin_of(uu[j]);
            if (b == 0)              ++cLo;
            else if (b == NBINS - 1) ++cHi;
            else atomicAdd(&hist[wave][b], 1u);
        }
        zr[it].x = uu[0]; zr[it].y = uu[1]; zr[it].z = uu[2]; zr[it].w = uu[3];
    }
    // wave-reduce the clamp-bin counts; one LDS atomic per wave per bin
#pragma unroll
    for (int off = 32; off >= 1; off >>= 1) {
        cLo += __shfl_down(cLo, off, 64);
        cHi += __shfl_down(cHi, off, 64);
    }
    if (lane == 0) {
        atomicAdd(&hist[wave][0],         cLo);
        atomicAdd(&hist[wave][NBINS - 1], cHi);
    }
    __syncthreads();

    // ---- per-thread 4-bin totals + shuffle-based block suffix scan ----
    const int hb = tid * (NBINS / NT);                        // 4 bins/thread
    uint32_t h[NBINS / NT];
    uint32_t cs = 0;
#pragma unroll
    for (int i = 0; i < NBINS / NT; ++i) {
        uint32_t t = 0;
#pragma unroll
        for (int c = 0; c < NWAVE; ++c) t += hist[c][hb + i];
        h[i] = t;
        cs += t;
    }
    uint32_t v = cs;                                          // wave suffix scan
#pragma unroll
    for (int off = 1; off < 64; off <<= 1) {
        uint32_t t = __shfl_down(v, off, 64);
        if (lane + off < 64) v += t;
    }
    if (lane == 0) wtot[wave] = v;
    __syncthreads();
    uint32_t above = 0;
#pragma unroll
    for (int c = 0; c < NWAVE; ++c) above += (c > wave) ? wtot[c] : 0u;
    uint32_t cum = (v + above) - cs;   // count in bins above my 4-bin chunk

    // unique writer also computes need2 directly (hist is final here)
    for (int i = NBINS / NT - 1; i >= 0; --i) {
        if (cum < KSEL && KSEL <= cum + h[i]) {
            const int Bq = hb + i;
            uint32_t hB1 = 0;
            if (Bq + 1 < NBINS) {
#pragma unroll
                for (int c = 0; c < NWAVE; ++c) hB1 += hist[c][Bq + 1];
            }
            s_B = Bq;
            // certain-1s = elements in bins > B+1 = cum - hB1
            s_need2 = KSEL - (int)(cum - hB1);
        }
        cum += h[i];
    }
    __syncthreads();
    const int B = s_B;
    const int need2 = s_need2;

    // ---- pass 2: classify, store, and resolve window owners INLINE ----
    float4* o4 = (float4*)(out + rbase);
#pragma unroll
    for (int it = 0; it < PT; ++it) {
        const int k = it * NT + tid;
        float uu[4] = {zr[it].x, zr[it].y, zr[it].z, zr[it].w};
        float oo[4];
#pragma unroll
        for (int j = 0; j < 4; ++j) {
            int b = bin_of(uu[j]);
            oo[j] = (b > B + 1) ? 1.0f : 0.0f;
            if (b >= B - 1 && b <= B + 1) {
                uint32_t slot = atomicAdd(&s_wcount, 1u);
                if (slot < WMAX) {
                    const int idx = k * 4 + j;
                    winIdx[slot] = idx;
                    // exact per-op-fp32-rounded chain; e,z are L1/L2-hot
                    // (this block just streamed them) -> short latency,
                    // overlapped with the surrounding store stream.
                    float e   = eps[rbase + idx];
                    float zz  = z[rbase + idx];
                    float l1  = (float)log((double)e);
                    float l2  = (float)log((double)(-l1));
                    float g   = -l2;
                    float s   = zz + g;
                    float t   = s / (2.0f / 3.0f);
                    float ex  = (float)exp(-(double)t);
                    float sig = 1.0f / (1.0f + ex);
                    winSig[slot] = __float_as_uint(sig);  // (0,1): uint order = float order
                }
            }
        }
        float4 ov; ov.x = oo[0]; ov.y = oo[1]; ov.z = oo[2]; ov.w = oo[3];
        o4[k] = ov;
    }
    // drains wide stores before the tail's scalar overwrites of same lines,
    // and publishes winIdx/winSig/s_wcount
    __syncthreads();

    // ---- rank-only tail: O(w^2) in LDS + scatter writes ----
    int w = (int)s_wcount; if (w > WMAX) w = WMAX;
    if (tid < 64) {
        for (int j = lane; j < w; j += 64) {
            uint32_t sj = winSig[j];
            int ij = winIdx[j];
            int rank = 0;
            for (int kk = 0; kk < w; ++kk) {
                uint32_t sk = winSig[kk];
                int ik = winIdx[kk];
                rank += (sk > sj || (sk == sj && ik < ij)) ? 1 : 0;
            }
            out[rbase + ij] = (rank < need2) ? 1.0f : 0.0f;
        }
    }
}

extern "C" void kernel_launch(void* const* d_in, const int* in_sizes, int n_in,
                              void* d_out, int out_size, void* d_ws, size_t ws_size,
                              hipStream_t stream) {
    const float* z   = (const float*)d_in[0];
    const float* eps = (const float*)d_in[1];
    float* out = (float*)d_out;
    hipLaunchKernelGGL(mask_topk_kernel, dim3(ROWS), dim3(NT), 0, stream,
                       z, eps, out);
}